// Round 12
// baseline (324.629 us; speedup 1.0000x reference)
//
#include <hip/hip_runtime.h>

// ---------------------------------------------------------------------------
// Attention_4956392259713 — round 19: faithful m201 8-phase port (all GEMMs).
// qkv = x@W^T+b; S = q@k^T (unscaled); P = softmax(S); out = P@v
//
// R8-R18: 11 schedule/depth variants all pin MfmaUtil 27-31%, total ~320+-3%.
// This round ports the verified 62%-MfmaUtil template (m201) EXACTLY:
//   BK=64, 2 K-tiles/iter, 8 phases/iter. Per phase:
//     {ds-read subtile (12/4/8/4 b128); stage 1 half-tile (2 gld16);
//      s_barrier; lgkmcnt(0); sched_barrier; setprio(1); 16 MFMA; setprio(0);
//      [vmcnt(6) at ph4/ph8 ONLY]; s_barrier}
//   Quadrant order ph1-4 (tile 2i, buf0): (A0,B0),(A0,B1),(A1,B1),(A1,B0);
//   ph5-8 = same for tile 2i+1 (buf1). A reused ph1-2/ph3-4; B1 reused
//   ph2-3; B0 re-read ph4/ph8 (keeps phases symmetric, frees B0 late).
//   Stage-halves = union of wave-local halves (A-first = tile rows 0-63 u
//   128-191 etc.) so each region's LAST ds_read is 1 phase before its stage:
//     ph1:B0(2i+1)  ph2:Af(2i+2) ph3:B1(2i+2) ph4:As(2i+2)
//     ph5:B0(2i+2)  ph6:Af(2i+3) ph7:B1(2i+3) ph8:As(2i+3)
//   FIFO proof: vmcnt(6) at ph4 leaves <=3 halves (this ph2,3,4) in flight ->
//   B0(2i+1) (staged ph1) landed for ph5; everything older landed. ph8
//   symmetric. Prologue stages 7 halves (vmcnt(4) after 4, vmcnt(6) after +3)
//   -> enter loop with 3 in flight = steady state. Last iter: ph4 vmcnt(0)
//   (ph2-4 stage nothing), ph8 no wait. Stages guarded by kt<ntile (uniform).
// Swizzle (128B rows, 8x16B units): U' = U ^ (row&7). Write side = linear
// gld16 dest + pre-swizzled GLOBAL k-column ((lane&7)^(lane>>3))*8 (rule #21);
// read side folded into per-lane ua0/ua1 (row&7 == ml&7 for all frag rows).
// Verified 0-conflict in R10 (same scheme).
// Numerics identical (fp16 QKV/QK^T; bf16 E and PV; no max subtraction).
// Fragment maps (m89-verified): A/B idx=lane&15, k=(lane>>4)*8+j;
//                               C/D col=lane&15, row=(lane>>4)*4+reg.
// ---------------------------------------------------------------------------

typedef short    s16x8 __attribute__((ext_vector_type(8)));
typedef _Float16 h16x8 __attribute__((ext_vector_type(8)));
typedef _Float16 h16x4 __attribute__((ext_vector_type(4)));
typedef float    f32x4 __attribute__((ext_vector_type(4)));

__device__ __forceinline__ unsigned short f2bf(float x) {
    unsigned u = __float_as_uint(x);
    u += 0x7fffu + ((u >> 16) & 1u);          // RTNE
    return (unsigned short)(u >> 16);
}
__device__ __forceinline__ float bf2f(unsigned short h) {
    return __uint_as_float(((unsigned)h) << 16);
}
__device__ __forceinline__ unsigned short f2h(float x) {
    _Float16 h = (_Float16)x;                 // v_cvt_f16_f32, RTNE
    unsigned short u;
    __builtin_memcpy(&u, &h, 2);
    return u;
}
__device__ __forceinline__ h16x8 as_h(s16x8 v) {
    h16x8 r; __builtin_memcpy(&r, &v, 16); return r;
}

// async global->LDS, 16 B per lane; LDS dest = wave-uniform base + lane*16
__device__ __forceinline__ void gld16(const void* g, void* l) {
    __builtin_amdgcn_global_load_lds(
        (const __attribute__((address_space(1))) unsigned int*)(unsigned long long)g,
        (__attribute__((address_space(3))) unsigned int*)(unsigned)(unsigned long long)l,
        16, 0, 0);
}

template<bool FP16>
__device__ __forceinline__ f32x4 mma(s16x8 a, s16x8 b, f32x4 c) {
    if constexpr (FP16)
        return __builtin_amdgcn_mfma_f32_16x16x32_f16(as_h(a), as_h(b), c, 0, 0, 0);
    else
        return __builtin_amdgcn_mfma_f32_16x16x32_bf16(a, b, c, 0, 0, 0);
}

// NT GEMM, 512 thr = 8 waves (2Mx4N), tile 256x256, BK=64, 8-phase m201 core.
// MODE 1: C = acc + bias -> fp16        [K1a]
// MODE 2: C = acc + bias -> bf16        [K1b]
// MODE 3: C = exp(acc)   -> bf16        [K2]
// MODE 4: C = acc * rvec[row] -> f32    [K4]  (rvec = 1/rowsum)
// SWZ 1: 3D batch-per-XCD; 2: 2D row-chunk-per-XCD (gridDim.y%8==0)
template<int MODE, bool FP16, int SWZ>
__global__ __launch_bounds__(512, 2)
void gemm_mfma(const unsigned short* __restrict__ A, const unsigned short* __restrict__ B,
               const float* __restrict__ bias, const float* __restrict__ rvec,
               float* __restrict__ Cf, unsigned short* __restrict__ Ch,
               int K, int lda, int ldb, int ldc,
               long long sA, long long sB, long long sC, long long sR)
{
    __shared__ unsigned short As[2][16384];   // per buf: 256 lds-rows x 64 k
    __shared__ unsigned short Bs[2][16384];

    int bx = blockIdx.x, by = blockIdx.y, bz = blockIdx.z;
    if (SWZ == 1) {
        const int l = bx + gridDim.x * (by + gridDim.y * bz);
        bz = l & 7;
        const int t = l >> 3;
        bx = t % gridDim.x;
        by = t / gridDim.x;
    } else if (SWZ == 2) {
        const int l = bx + gridDim.x * by;
        const int c = l & 7;
        const int t = l >> 3;
        const int rows = gridDim.y >> 3;
        bx = t % gridDim.x;
        by = c * rows + t / gridDim.x;
    }

    A += (long long)bz * sA;
    B += (long long)bz * sB;

    const long long m0 = (long long)by * 256;
    const long long n0 = (long long)bx * 256;

    const int tid  = threadIdx.x;
    const int wave = tid >> 6, lane = tid & 63;
    const int wr = wave >> 2, wc = wave & 3;             // 2M x 4N wave grid
    const int ml = lane & 15;                            // fragment row-in-16
    // swizzled k-units for fragment reads: U' = U ^ (row&7), row&7 == ml&7
    const int ua0 = (((lane >> 4)    ) ^ (ml & 7)) * 8;  // kstep 0, elems
    const int ua1 = (((lane >> 4) + 4) ^ (ml & 7)) * 8;  // kstep 1
    // staging: srow in [0,64), pre-swizzled global k-column
    const int srow = wave * 8 + (lane >> 3);
    const int skc  = ((lane & 7) ^ (lane >> 3)) * 8;
    const int sc5 = srow >> 5, s31 = srow & 31;

    // fragment read base offsets (elems); + h*8192 + i*1024 + ua
    const int aro = (wr * 64 + ml) * 64;
    const int bro = (wc * 32 + ml) * 64;

    const int ntile = K >> 6;                 // 64-elem K-tiles
    const int npair = ntile >> 1;             // iterations (2 tiles each)

    const unsigned short* Asrc = A + (m0 + srow) * (long long)lda + skc;
    const unsigned short* Bsrc = B + (n0 + s31) * (long long)ldb + skc;

    // stage one 16KB half: A stage-half h = tile rows {h*64..+63, 128+h*64..}
    auto stA = [&](int kt, int buf, int h) {
        if (kt >= ntile) return;
#pragma unroll
        for (int c = 0; c < 2; ++c)
            gld16(Asrc + (long long)(h * 64 + c * 128) * lda + kt * 64,
                  &As[buf][(h * 128 + c * 64 + wave * 8) * 64]);
    };
    // B stage-half hB = tile cols U_wc [wc*64+hB*32, +32)
    auto stB = [&](int kt, int buf, int hB) {
        if (kt >= ntile) return;
#pragma unroll
        for (int c = 0; c < 2; ++c)
            gld16(Bsrc + (long long)((c * 2 + sc5) * 64 + hB * 32) * ldb + kt * 64,
                  &Bs[buf][(hB * 128 + c * 64 + wave * 8) * 64]);
    };

    s16x8 af[4][2], bf0[2][2], bf1[2][2];
    auto ldA = [&](const unsigned short* bp, int h) {
#pragma unroll
        for (int i = 0; i < 4; ++i) {
            af[i][0] = *(const s16x8*)&bp[h * 8192 + aro + i * 1024 + ua0];
            af[i][1] = *(const s16x8*)&bp[h * 8192 + aro + i * 1024 + ua1];
        }
    };
    auto ldB = [&](const unsigned short* bp, int hB, s16x8 bf[2][2]) {
#pragma unroll
        for (int jj = 0; jj < 2; ++jj) {
            bf[jj][0] = *(const s16x8*)&bp[hB * 8192 + bro + jj * 1024 + ua0];
            bf[jj][1] = *(const s16x8*)&bp[hB * 8192 + bro + jj * 1024 + ua1];
        }
    };

    f32x4 acc[8][4];
#pragma unroll
    for (int i = 0; i < 8; ++i)
#pragma unroll
        for (int j = 0; j < 4; ++j) acc[i][j] = f32x4{0.f, 0.f, 0.f, 0.f};

    auto mfmaQ = [&](int ib, int jb, s16x8 bf[2][2]) {
        __builtin_amdgcn_s_setprio(1);
#pragma unroll
        for (int s = 0; s < 2; ++s)
#pragma unroll
            for (int i = 0; i < 4; ++i)
#pragma unroll
                for (int jj = 0; jj < 2; ++jj)
                    acc[ib + i][jb + jj] = mma<FP16>(af[i][s], bf[jj][s], acc[ib + i][jb + jj]);
        __builtin_amdgcn_s_setprio(0);
    };

#define PH_SYNC  __builtin_amdgcn_s_barrier();                              \
                 asm volatile("s_waitcnt lgkmcnt(0)" ::: "memory");          \
                 __builtin_amdgcn_sched_barrier(0);
#define PH_END   __builtin_amdgcn_s_barrier();                              \
                 __builtin_amdgcn_sched_barrier(0);

    // prologue: 7 half-tiles — Af(0),B0(0) | B1(0),As(0) | vm(4) | Af(1),B1(1),As(1) | vm(6)
    stA(0, 0, 0); stB(0, 0, 0);
    stB(0, 0, 1); stA(0, 0, 1);
    asm volatile("s_waitcnt vmcnt(4)" ::: "memory");
    stA(1, 1, 0); stB(1, 1, 1); stA(1, 1, 1);
    asm volatile("s_waitcnt vmcnt(6)" ::: "memory");
    __builtin_amdgcn_s_barrier();
    __builtin_amdgcn_sched_barrier(0);

    for (int it = 0; it < npair; ++it) {
        const int ta = 2 * it, tb = 2 * it + 1;
        const bool last = (it == npair - 1);
        const unsigned short* a0 = &As[0][0];
        const unsigned short* b0 = &Bs[0][0];
        const unsigned short* a1 = &As[1][0];
        const unsigned short* b1 = &Bs[1][0];

        // ph1: A(buf0,h0)+B(buf0,hB0) [12 rd]; stage B0(tb)->buf1
        ldA(a0, 0); ldB(b0, 0, bf0);
        stB(tb, 1, 0);
        PH_SYNC; mfmaQ(0, 0, bf0); PH_END;

        // ph2: B(buf0,hB1) [4 rd]; stage Af(ta+2)->buf0
        ldB(b0, 1, bf1);
        stA(ta + 2, 0, 0);
        PH_SYNC; mfmaQ(0, 2, bf1); PH_END;

        // ph3: A(buf0,h1) [8 rd]; stage B1(ta+2)->buf0
        ldA(a0, 1);
        stB(ta + 2, 0, 1);
        PH_SYNC; mfmaQ(4, 2, bf1); PH_END;

        // ph4: B(buf0,hB0) re-read [4 rd]; stage As(ta+2)->buf0; counted vm
        ldB(b0, 0, bf0);
        stA(ta + 2, 0, 1);
        PH_SYNC; mfmaQ(4, 0, bf0);
        if (!last) { asm volatile("s_waitcnt vmcnt(6)" ::: "memory"); }
        else       { asm volatile("s_waitcnt vmcnt(0)" ::: "memory"); }
        PH_END;

        // ph5: A(buf1,h0)+B(buf1,hB0) [12 rd]; stage B0(ta+2)->buf0
        ldA(a1, 0); ldB(b1, 0, bf0);
        stB(ta + 2, 0, 0);
        PH_SYNC; mfmaQ(0, 0, bf0); PH_END;

        // ph6: B(buf1,hB1) [4 rd]; stage Af(tb+2)->buf1
        ldB(b1, 1, bf1);
        stA(tb + 2, 1, 0);
        PH_SYNC; mfmaQ(0, 2, bf1); PH_END;

        // ph7: A(buf1,h1) [8 rd]; stage B1(tb+2)->buf1
        ldA(a1, 1);
        stB(tb + 2, 1, 1);
        PH_SYNC; mfmaQ(4, 2, bf1); PH_END;

        // ph8: B(buf1,hB0) re-read [4 rd]; stage As(tb+2)->buf1; counted vm
        ldB(b1, 0, bf0);
        stA(tb + 2, 1, 1);
        PH_SYNC; mfmaQ(4, 0, bf0);
        if (it + 1 < npair) { asm volatile("s_waitcnt vmcnt(6)" ::: "memory"); }
        PH_END;
    }
#undef PH_SYNC
#undef PH_END

    // ---- epilogue: C/D map col=lane&15, row=(lane>>4)*4+reg
    const int r0 = (lane >> 4) * 4;
    const long long rowbase = m0 + wr * 128 + r0;
    const long long colbase = n0 + wc * 64 + ml;
    if (MODE == 1 || MODE == 2) {
#pragma unroll
        for (int i = 0; i < 8; ++i) {
            const long long rowb = rowbase + i * 16;
#pragma unroll
            for (int j = 0; j < 4; ++j) {
                const long long col = colbase + j * 16;
                const float bj = bias[col];
#pragma unroll
                for (int q = 0; q < 4; ++q) {
                    const float vv = acc[i][j][q] + bj;
                    Ch[(rowb + q) * (long long)ldc + col] = (MODE == 1) ? f2h(vv) : f2bf(vv);
                }
            }
        }
    } else if (MODE == 3) {
        Ch += (long long)bz * sC;
#pragma unroll
        for (int i = 0; i < 8; ++i) {
            const long long rowb = rowbase + i * 16;
#pragma unroll
            for (int j = 0; j < 4; ++j) {
                const long long col = colbase + j * 16;
#pragma unroll
                for (int q = 0; q < 4; ++q)
                    Ch[(rowb + q) * (long long)ldc + col] = f2bf(__expf(acc[i][j][q]));
            }
        }
    } else {   // MODE 4
        Cf += (long long)bz * sC;
        rvec += (long long)bz * sR;
#pragma unroll
        for (int i = 0; i < 8; ++i) {
            const long long rowb = rowbase + i * 16;
#pragma unroll
            for (int j = 0; j < 4; ++j) {
                const long long col = colbase + j * 16;
#pragma unroll
                for (int q = 0; q < 4; ++q)
                    Cf[(rowb + q) * (long long)ldc + col] = acc[i][j][q] * rvec[rowb + q];
            }
        }
    }
}

// f32 -> fp16 convert, 4 elems/thread, two source buffers in one launch
__global__ __launch_bounds__(256)
void cvt_f16_2(const float* __restrict__ a, long long na4,
               const float* __restrict__ b, long long nb4,
               unsigned short* __restrict__ oa, unsigned short* __restrict__ ob)
{
    const long long i = (long long)blockIdx.x * 256 + threadIdx.x;
    const float4* src;
    h16x4* dst;
    long long idx;
    if (i < na4)            { src = (const float4*)a; dst = (h16x4*)oa; idx = i; }
    else if (i < na4 + nb4) { src = (const float4*)b; dst = (h16x4*)ob; idx = i - na4; }
    else return;
    const float4 v = src[idx];
    h16x4 o;
    o.x = (_Float16)v.x; o.y = (_Float16)v.y;
    o.z = (_Float16)v.z; o.w = (_Float16)v.w;
    dst[idx] = o;
}

// vt[b][h][n] = v[b*2048+n][h]   (V transpose, bf16)
__global__ __launch_bounds__(256)
void transpose_v(const unsigned short* __restrict__ v, unsigned short* __restrict__ vt)
{
    __shared__ unsigned short t[32][33];
    const int b = blockIdx.z;
    const int n0 = blockIdx.x * 32, h0 = blockIdx.y * 32;
    const int tx = threadIdx.x, ty = threadIdx.y;      // 32 x 8
    const unsigned short* src = v + (long long)b * 2048 * 768;
#pragma unroll
    for (int q = 0; q < 4; ++q)
        t[ty + q * 8][tx] = src[(long long)(n0 + ty + q * 8) * 768 + h0 + tx];
    __syncthreads();
    unsigned short* dst = vt + ((long long)b * 768 + h0) * 2048 + n0;
#pragma unroll
    for (int q = 0; q < 4; ++q)
        dst[(long long)(ty + q * 8) * 2048 + tx] = t[tx][ty + q * 8];
}

// r[row] = 1 / sum(E[row][0:2048])   (E bf16, one 256-thr block per row)
__global__ __launch_bounds__(256)
void rowsum_recip(const unsigned short* __restrict__ E, float* __restrict__ r)
{
    const long long row = blockIdx.x;
    const int t = threadIdx.x, lane = t & 63, w = t >> 6;
    __shared__ float red[4];
    const uint4 v = ((const uint4*)(E + row * 2048))[t];   // 8 bf16
    float s = bf2f((unsigned short)(v.x & 0xffff)) + bf2f((unsigned short)(v.x >> 16))
            + bf2f((unsigned short)(v.y & 0xffff)) + bf2f((unsigned short)(v.y >> 16))
            + bf2f((unsigned short)(v.z & 0xffff)) + bf2f((unsigned short)(v.z >> 16))
            + bf2f((unsigned short)(v.w & 0xffff)) + bf2f((unsigned short)(v.w >> 16));
#pragma unroll
    for (int o = 32; o; o >>= 1) s += __shfl_xor(s, o);
    if (lane == 0) red[w] = s;
    __syncthreads();
    if (t == 0) r[row] = 1.f / ((red[0] + red[1]) + (red[2] + red[3]));
}

extern "C" void kernel_launch(void* const* d_in, const int* in_sizes, int n_in,
                              void* d_out, int out_size, void* d_ws, size_t ws_size,
                              hipStream_t stream)
{
    const float* x    = (const float*)d_in[0];   // [16384, 768]
    const float* W    = (const float*)d_in[1];   // [2304, 768]
    const float* bias = (const float*)d_in[2];   // [2304]
    float* out = (float*)d_out;                  // [8, 2048, 768]

    // ---- workspace layout (bytes), total 196.5 MB
    char* ws = (char*)d_ws;
    unsigned short* xh = (unsigned short*)ws;                      // [16384,768] fp16
    unsigned short* Wh = (unsigned short*)(ws + 25165824LL);       // [2304,768] fp16
    unsigned short* qk = (unsigned short*)(ws + 28704768LL);       // [16384,1536] fp16
    unsigned short* v  = (unsigned short*)(ws + 79036416LL);       // [16384,768] bf16
    unsigned short* vt = (unsigned short*)(ws + 104202240LL);      // [8,768,2048] bf16
    unsigned short* E  = (unsigned short*)(ws + 129368064LL);      // [8,2048,2048] bf16
    float*          r  = (float*)(ws + 196476928LL);               // [16384] f32

    // C1+C2: convert x and W to fp16 in one launch
    cvt_f16_2<<<dim3(14016), dim3(256), 0, stream>>>(
        x, 3145728LL, W, 442368LL, xh, Wh);

    // K1a: qk = x @ Wqk^T + b  (fp16, M=16384 N=1536 K=768)
    gemm_mfma<1, true, 2><<<dim3(6, 64, 1), dim3(512), 0, stream>>>(
        xh, Wh, bias, nullptr, nullptr, qk,
        768, 768, 768, 1536, 0, 0, 0, 0);

    // K1b: v = x @ Wv^T + b -> bf16  (M=16384 N=768 K=768)
    gemm_mfma<2, true, 2><<<dim3(3, 64, 1), dim3(512), 0, stream>>>(
        xh, Wh + 1536LL * 768, bias + 1536, nullptr, nullptr, v,
        768, 768, 768, 768, 0, 0, 0, 0);

    // T: vt = v^T per batch
    transpose_v<<<dim3(64, 24, 8), dim3(32, 8), 0, stream>>>(v, vt);

    // K2: E = exp(q @ k^T)  (fp16, M=N=2048 K=768, z=8), batch-per-XCD
    gemm_mfma<3, true, 1><<<dim3(8, 8, 8), dim3(512), 0, stream>>>(
        qk, qk + 768, nullptr, nullptr, nullptr, E,
        768, 1536, 1536, 2048,
        2048LL * 1536, 2048LL * 1536, 2048LL * 2048, 0);

    // K3': r = 1/rowsum(E)
    rowsum_recip<<<dim3(16384), dim3(256), 0, stream>>>(E, r);

    // K4: out = (E @ vt^T) * r[row]  (bf16, M=2048 N=768 K=2048, z=8)
    gemm_mfma<4, false, 1><<<dim3(3, 8, 8), dim3(512), 0, stream>>>(
        E, vt, nullptr, r, out, nullptr,
        2048, 2048, 2048, 768,
        2048LL * 2048, 768LL * 2048, 2048LL * 768, 2048);
}